// Round 6
// baseline (46.149 us; speedup 1.0000x reference)
//
#include <hip/hip_runtime.h>

typedef _Float16 h2 __attribute__((ext_vector_type(2)));
typedef _Float16 h8 __attribute__((ext_vector_type(8)));

#define RANK  16
#define GRIDP 128
#define BLOCK 256
#define NBLK  4096

union H8 { h8 v; h2 p[4]; };

__device__ __forceinline__ float fdot2(h2 a, h2 b, float c) {
#if __has_builtin(__builtin_amdgcn_fdot2)
    return __builtin_amdgcn_fdot2(a, b, c, false);
#else
    return (float)a.x * (float)b.x + (float)a.y * (float)b.y + c;
#endif
}

// Build chunked f16 table in workspace: gt[a][c][g] = ranks 8c..8c+7 of grid
// row g, 16B entries. Identical layout to the LDS copy; stays L1-resident.
__global__ void pinn_prep_kernel(const float* __restrict__ line,
                                 _Float16* __restrict__ gt) {
    int i = threadIdx.x + blockIdx.x * blockDim.x;
    if (i < 3 * RANK * GRIDP) {
        int a = i >> 11;          // / (16*128)
        int r = (i >> 7) & 15;    // rank
        int g = i & 127;          // grid row
        int c = r >> 3;           // rank half
        gt[((((a << 1) + c) << 7) + g) * 8 + (r & 7)] = (_Float16)line[i];
    }
}

__global__ __launch_bounds__(BLOCK) void pinn_lora_kernel(
    const float* __restrict__ x, const float* __restrict__ line,
    const float* __restrict__ W, const h8* __restrict__ gt8,
    float* __restrict__ out, int npts)
{
    // Full chunked fp16 table in LDS (12 KiB): tab[a][c][g], 16B entries.
    __shared__ h8 tab[3][2][GRIDP];

    _Float16* t = (_Float16*)tab;
    for (int i = threadIdx.x; i < 3 * RANK * GRIDP; i += BLOCK) {
        int a = i >> 11;
        int r = (i >> 7) & 15;
        int g = i & 127;
        int c = r >> 3;
        t[((((a << 1) + c) << 7) + g) * 8 + (r & 7)] = (_Float16)line[i];
    }

    // W[3][16] f32 -> packed f16 (uniform scalar loads)
    h2 Wp[3][8];
#pragma unroll
    for (int o = 0; o < 3; ++o)
#pragma unroll
        for (int d = 0; d < 8; ++d) {
            Wp[o][d].x = (_Float16)W[o * 16 + 2 * d];
            Wp[o][d].y = (_Float16)W[o * 16 + 2 * d + 1];
        }

    __syncthreads();

    int tid    = blockIdx.x * BLOCK + threadIdx.x;
    int stride = gridDim.x * BLOCK;

    for (int p = tid; p < npts; p += stride) {
        // streaming I/O nontemporal: don't evict the table from L1
        float cx = __builtin_nontemporal_load(x + 3 * p + 0);
        float cy = __builtin_nontemporal_load(x + 3 * p + 1);
        float cz = __builtin_nontemporal_load(x + 3 * p + 2);
        float crd[3] = {cz, cy, cx};   // axis a interpolates x[:, 2-a]

        int idx[3];
        h2  wv[3];
#pragma unroll
        for (int a = 0; a < 3; ++a) {
            float pos = fmaf(crd[a], 63.5f, 63.5f);
            int   i0  = (int)pos;              // pos >= 0 -> trunc == floor
            i0 = (i0 > 126) ? 126 : i0;
            float w = pos - (float)i0;
            _Float16 wh = (_Float16)w;
            h2 w2; w2.x = wh; w2.y = wh;
            idx[a] = i0;
            wv[a]  = w2;
        }

        // VMEM: 3 of the 12 granules, from the L1-resident global copy.
        // (axis0 c1 rows i0,i0+1 ; axis1 c1 row i0+1) -- issue early.
        H8 vA, vB, vC;
        vA.v = gt8[(0 * 2 + 1) * GRIDP + idx[0]];
        vB.v = gt8[(0 * 2 + 1) * GRIDP + idx[0] + 1];
        vC.v = gt8[(1 * 2 + 1) * GRIDP + idx[1] + 1];

        // LDS: the remaining 9 granules.
        H8 A00, B00, A10, B10, A11, A20, B20, A21, B21;
        A00.v = tab[0][0][idx[0]];  B00.v = tab[0][0][idx[0] + 1];
        A10.v = tab[1][0][idx[1]];  B10.v = tab[1][0][idx[1] + 1];
        A11.v = tab[1][1][idx[1]];
        A20.v = tab[2][0][idx[2]];  B20.v = tab[2][0][idx[2] + 1];
        A21.v = tab[2][1][idx[2]];  B21.v = tab[2][1][idx[2] + 1];

        // ranks 0..7 : all-LDS
        H8 prod0;
#pragma unroll
        for (int j = 0; j < 4; ++j) {
            h2 v0 = A00.p[j] + (B00.p[j] - A00.p[j]) * wv[0];
            h2 v1 = A10.p[j] + (B10.p[j] - A10.p[j]) * wv[1];
            h2 v2 = A20.p[j] + (B20.p[j] - A20.p[j]) * wv[2];
            prod0.p[j] = v0 * v1 * v2;
        }

        // ranks 8..15 : axis0 from VMEM, axis1 mixed, axis2 LDS
        H8 prod1;
#pragma unroll
        for (int j = 0; j < 4; ++j) {
            h2 v0 = vA.p[j]  + (vB.p[j] - vA.p[j])  * wv[0];
            h2 v1 = A11.p[j] + (vC.p[j] - A11.p[j]) * wv[1];
            h2 v2 = A21.p[j] + (B21.p[j] - A21.p[j]) * wv[2];
            prod1.p[j] = v0 * v1 * v2;
        }

#pragma unroll
        for (int oo = 0; oo < 3; ++oo) {
            float acc = 0.f;
#pragma unroll
            for (int j = 0; j < 4; ++j) {
                acc = fdot2(prod0.p[j], Wp[oo][j],     acc);
                acc = fdot2(prod1.p[j], Wp[oo][j + 4], acc);
            }
            __builtin_nontemporal_store(acc, out + 3 * p + oo);
        }
    }
}

extern "C" void kernel_launch(void* const* d_in, const int* in_sizes, int n_in,
                              void* d_out, int out_size, void* d_ws, size_t ws_size,
                              hipStream_t stream) {
    const float* x    = (const float*)d_in[0];   // [N,3] f32
    const float* line = (const float*)d_in[1];   // [3,16,128] f32
    const float* W    = (const float*)d_in[2];   // [3,16] f32
    float*       out  = (float*)d_out;           // [N,3] f32
    _Float16*    gt   = (_Float16*)d_ws;         // 12 KiB chunked f16 table

    int npts = in_sizes[0] / 3;

    pinn_prep_kernel<<<(3 * RANK * GRIDP + BLOCK - 1) / BLOCK, BLOCK, 0, stream>>>(line, gt);
    pinn_lora_kernel<<<NBLK, BLOCK, 0, stream>>>(x, line, W, (const h8*)gt, out, npts);
}

// Round 7
// 30.399 us; speedup vs baseline: 1.5181x; 1.5181x over previous
//
#include <hip/hip_runtime.h>

typedef _Float16 h2 __attribute__((ext_vector_type(2)));
typedef _Float16 h8 __attribute__((ext_vector_type(8)));

#define RANK  16
#define GRIDP 128
#define BLOCK 256
#define NBLK  1024   // 4 blocks/CU; 262144 threads x 4 groups = 1048576 groups

union H8 { h8 v; h2 p[4]; _Float16 e[8]; };

__device__ __forceinline__ float fdot2(h2 a, h2 b, float c) {
#if __has_builtin(__builtin_amdgcn_fdot2)
    return __builtin_amdgcn_fdot2(a, b, c, false);
#else
    return (float)a.x * (float)b.x + (float)a.y * (float)b.y + c;
#endif
}

__global__ __launch_bounds__(BLOCK, 4) void pinn_lora_kernel(
    const float* __restrict__ x, const float* __restrict__ line,
    const float* __restrict__ W, float* __restrict__ out, int ngroups)
{
    // Chunked fp16 table: tab[a][c][g] = ranks 8c..8c+7 of grid row g (16B).
    // 16B entries at 16B stride -> bank-quad class = g & 7 (max spread for b128).
    __shared__ h8 tab[3][2][GRIDP];

    // Prologue: one thread per 16B granule. For fixed rank j, lanes sweep g ->
    // fully coalesced global dword loads; ds_write_b128 lands 8 lanes/class at
    // distinct addresses = the 8-phase minimum.
    for (int q = threadIdx.x; q < 3 * 2 * GRIDP; q += BLOCK) {
        int a = q >> 8;           // axis 0..2
        int c = (q >> 7) & 1;     // rank half
        int g = q & 127;          // grid row
        const float* src = line + (a * RANK + c * 8) * GRIDP + g;
        H8 v;
#pragma unroll
        for (int j = 0; j < 8; ++j)
            v.e[j] = (_Float16)src[j * GRIDP];
        tab[a][c][g] = v.v;
    }

    // W[3][16] f32 -> packed f16 (uniform -> scalar loads, stays in SGPRs)
    h2 Wp[3][8];
#pragma unroll
    for (int o = 0; o < 3; ++o)
#pragma unroll
        for (int d = 0; d < 8; ++d) {
            Wp[o][d].x = (_Float16)W[o * 16 + 2 * d];
            Wp[o][d].y = (_Float16)W[o * 16 + 2 * d + 1];
        }

    __syncthreads();

    const float4* xv = (const float4*)x;
    float4*       ov = (float4*)out;

    int tid = blockIdx.x * BLOCK + threadIdx.x;

#pragma unroll
    for (int grp = 0; grp < 4; ++grp) {
        int g = tid + grp * (NBLK * BLOCK);
        if (g >= ngroups) break;

        float4 c0 = xv[3 * g + 0];
        float4 c1 = xv[3 * g + 1];
        float4 c2 = xv[3 * g + 2];

        // 4 points per group; x layout [N][3]
        float cx[4] = {c0.x, c0.w, c1.z, c2.y};   // x[:,0]
        float cy[4] = {c0.y, c1.x, c1.w, c2.z};   // x[:,1]
        float cz[4] = {c0.z, c1.y, c2.x, c2.w};   // x[:,2]

        float o[4][3];
#pragma unroll
        for (int p = 0; p < 4; ++p) {
            // axis a interpolates coord x[:, 2-a]
            float crd[3] = {cz[p], cy[p], cx[p]};
            H8 prod0, prod1;
#pragma unroll
            for (int a = 0; a < 3; ++a) {
                float pos = fmaf(crd[a], 63.5f, 63.5f);
                int   i0  = (int)pos;              // pos >= 0 -> trunc == floor
                i0 = (i0 > 126) ? 126 : i0;
                float w = pos - (float)i0;
                _Float16 wh = (_Float16)w;
                h2 w2; w2.x = wh; w2.y = wh;

                H8 A0, A1, B0, B1;
                A0.v = tab[a][0][i0];     // row i0,   ranks 0..7
                B0.v = tab[a][0][i0 + 1]; // row i0+1, ranks 0..7
                A1.v = tab[a][1][i0];     // row i0,   ranks 8..15
                B1.v = tab[a][1][i0 + 1]; // row i0+1, ranks 8..15

                H8 v0, v1;
#pragma unroll
                for (int j = 0; j < 4; ++j) {
                    v0.p[j] = A0.p[j] + (B0.p[j] - A0.p[j]) * w2;
                    v1.p[j] = A1.p[j] + (B1.p[j] - A1.p[j]) * w2;
                }
                if (a == 0) { prod0 = v0; prod1 = v1; }
                else {
#pragma unroll
                    for (int j = 0; j < 4; ++j) {
                        prod0.p[j] *= v0.p[j];
                        prod1.p[j] *= v1.p[j];
                    }
                }
            }
#pragma unroll
            for (int oo = 0; oo < 3; ++oo) {
                float acc = 0.f;
#pragma unroll
                for (int j = 0; j < 4; ++j) {
                    acc = fdot2(prod0.p[j], Wp[oo][j],     acc);
                    acc = fdot2(prod1.p[j], Wp[oo][j + 4], acc);
                }
                o[p][oo] = acc;
            }
        }

        float4 s0 = {o[0][0], o[0][1], o[0][2], o[1][0]};
        float4 s1 = {o[1][1], o[1][2], o[2][0], o[2][1]};
        float4 s2 = {o[2][2], o[3][0], o[3][1], o[3][2]};
        ov[3 * g + 0] = s0;
        ov[3 * g + 1] = s1;
        ov[3 * g + 2] = s2;
    }
}

extern "C" void kernel_launch(void* const* d_in, const int* in_sizes, int n_in,
                              void* d_out, int out_size, void* d_ws, size_t ws_size,
                              hipStream_t stream) {
    const float* x    = (const float*)d_in[0];   // [N,3] f32
    const float* line = (const float*)d_in[1];   // [3,16,128] f32
    const float* W    = (const float*)d_in[2];   // [3,16] f32
    float*       out  = (float*)d_out;           // [N,3] f32

    int npts    = in_sizes[0] / 3;
    int ngroups = npts / 4;                      // N = 2^22 -> 1048576 groups

    pinn_lora_kernel<<<NBLK, BLOCK, 0, stream>>>(x, line, W, out, ngroups);
}